// Round 5
// baseline (905.880 us; speedup 1.0000x reference)
//
#include <hip/hip_runtime.h>
#include <math.h>

// ---------------------------------------------------------------------------
// GATv2 2-layer GNN (N=50000, E=800000, IN=W=128, HEADS=4, HID=32, EDIM=16)
// Strategy:
//   1. per-node mean of incoming edge_attr (self-loop attr)   [atomics]
//   2. build dst-sorted CSR (hist -> scan -> scatter)          [once/launch]
//   3. per layer: xl/xr = in@[Wl|Wr]+bias  (f32 GEMM, LDS A-tile)
//   4. per layer: one WAVE per node, online softmax over incoming edges,
//      single xl[src] gather per edge, everything in registers.
//   5. classifier dot product.
// NOTE: harness passes ALL integer inputs as int32 ("integer -> const int*"),
// even though the reference uses int64 edge_index. Round-2 crash was reading
// it as long long. Indices are defensively clamped so a future surprise
// fails absmax instead of core-dumping.
// ---------------------------------------------------------------------------

static inline size_t align256(size_t x) { return (x + 255) & ~size_t(255); }

__device__ __forceinline__ int clampi(int v, int lo, int hi) {
  return v < lo ? lo : (v > hi ? hi : v);
}

// ---- self-loop attr: sum + count per dst -----------------------------------
__global__ void k_loop_accum(const int* __restrict__ ei, const float* __restrict__ ea,
                             float* __restrict__ lsum, int* __restrict__ cnt, int E, int n) {
  int i = blockIdx.x * blockDim.x + threadIdx.x;
  if (i >= E * 16) return;
  int e = i >> 4, d = i & 15;
  int dst = clampi(ei[E + e], 0, n - 1);
  atomicAdd(&lsum[dst * 16 + d], ea[i]);
  if (d == 0) atomicAdd(&cnt[dst], 1);
}

__global__ void k_loop_final(float* __restrict__ lsum, const int* __restrict__ cnt, int n) {
  int i = blockIdx.x * blockDim.x + threadIdx.x;
  if (i >= n * 16) return;
  int node = i >> 4;
  int c = cnt[node];
  lsum[i] = lsum[i] / (float)(c > 1 ? c : 1);
}

// ---- exclusive scan of (cnt[i]+1) over n nodes, single block of 512 --------
__global__ void k_scan(const int* __restrict__ cnt, int* __restrict__ row_ptr, int n) {
  const int T = 512;
  __shared__ int wsum[8], wbase[8];
  int tid = threadIdx.x;
  int chunk = (n + T - 1) / T;
  int lo = tid * chunk; if (lo > n) lo = n;
  int hi = lo + chunk;  if (hi > n) hi = n;
  int s = 0;
  for (int i = lo; i < hi; ++i) s += cnt[i] + 1;
  int lane = tid & 63, w = tid >> 6;
  int incl = s;
  #pragma unroll
  for (int d = 1; d < 64; d <<= 1) {
    int v = __shfl_up(incl, d, 64);
    if (lane >= d) incl += v;
  }
  if (lane == 63) wsum[w] = incl;
  __syncthreads();
  if (tid == 0) {
    int a = 0;
    for (int i = 0; i < 8; ++i) { wbase[i] = a; a += wsum[i]; }
  }
  __syncthreads();
  int run = wbase[w] + (incl - s);   // exclusive prefix at this thread's chunk
  if (tid == 0) row_ptr[0] = 0;
  for (int i = lo; i < hi; ++i) { run += cnt[i] + 1; row_ptr[i + 1] = run; }
}

// ---- scatter edges (and self-loops) into CSR -------------------------------
__global__ void k_scatter(const int* __restrict__ ei, int* __restrict__ cursor,
                          int* __restrict__ col_src, int* __restrict__ col_eid, int E, int n) {
  int i = blockIdx.x * blockDim.x + threadIdx.x;
  if (i < E) {
    int src = clampi(ei[i], 0, n - 1);
    int dst = clampi(ei[E + i], 0, n - 1);
    int pos = atomicAdd(&cursor[dst], 1);
    col_src[pos] = src;
    col_eid[pos] = i;
  } else if (i < E + n) {
    int node = i - E;
    int pos = atomicAdd(&cursor[node], 1);
    col_src[pos] = node;
    col_eid[pos] = E + node;     // eid >= E marks a self-loop -> loop_attr
  }
}

// ---- node transform: xl = in@Wl+bl, xr = in@Wr+br (fused, 256 cols) --------
// block = 256 threads (thread c -> output col; c<128: Wl, else Wr), 16 rows.
__launch_bounds__(256)
__global__ void k_transform(const float* __restrict__ in, const float* __restrict__ Wl,
                            const float* __restrict__ bl, const float* __restrict__ Wr,
                            const float* __restrict__ br, float* __restrict__ xl,
                            float* __restrict__ xr, int n) {
  __shared__ float As[16][128];
  int tid = threadIdx.x;
  int row0 = blockIdx.x * 16;
  int rows = n - row0; if (rows > 16) rows = 16;
  const float4* in4 = (const float4*)(in + (size_t)row0 * 128);
  float4* As4 = (float4*)As;
  for (int i = tid; i < rows * 32; i += 256) As4[i] = in4[i];
  __syncthreads();
  int c = tid;
  const float* B = (c < 128) ? Wl : Wr;
  int cc = c & 127;
  float bias = (c < 128) ? bl[cc] : br[cc];
  float acc[16];
  #pragma unroll
  for (int i = 0; i < 16; ++i) acc[i] = bias;
  for (int k = 0; k < 128; k += 4) {
    float b0 = B[(k + 0) * 128 + cc], b1 = B[(k + 1) * 128 + cc];
    float b2 = B[(k + 2) * 128 + cc], b3 = B[(k + 3) * 128 + cc];
    #pragma unroll
    for (int r = 0; r < 16; ++r) {
      float4 a = *(const float4*)&As[r][k];   // LDS broadcast (uniform addr)
      acc[r] += a.x * b0 + a.y * b1 + a.z * b2 + a.w * b3;
    }
  }
  float* op = (c < 128) ? xl : xr;
  for (int r = 0; r < rows; ++r) op[(size_t)(row0 + r) * 128 + cc] = acc[r];
}

// ---- GATv2 aggregation: one wave per node, online softmax ------------------
// lane handles channels (2*lane, 2*lane+1) -> both in head (lane>>4).
// e_h reduction: shfl_xor butterfly over the 16-lane head group.
// unroll 4: index loads are chain-independent -> 4 gathers in flight.
__launch_bounds__(256)
__global__ void k_aggregate(const float* __restrict__ xl, const float* __restrict__ xr,
                            const int* __restrict__ row_ptr, const int* __restrict__ col_src,
                            const int* __restrict__ col_eid, const float* __restrict__ ea,
                            const float* __restrict__ loop_attr, const float* __restrict__ We,
                            const float* __restrict__ att, const float* __restrict__ bvec,
                            float* __restrict__ out, int n, int E) {
  int wv = threadIdx.x >> 6, lane = threadIdx.x & 63;
  int node = blockIdx.x * 4 + wv;
  if (node >= n) return;
  int c0 = lane * 2, c1 = lane * 2 + 1;
  // We columns for this lane's two channels, kept in registers (32 VGPRs)
  float we0[16], we1[16];
  #pragma unroll
  for (int d = 0; d < 16; ++d) {
    we0[d] = We[d * 128 + c0];
    we1[d] = We[d * 128 + c1];
  }
  float att0 = att[c0], att1 = att[c1];   // att flat index == channel index
  float2 xrv = ((const float2*)(xr + (size_t)node * 128))[lane];
  float mx = -INFINITY, den = 0.f, acc0 = 0.f, acc1 = 0.f;
  int beg = row_ptr[node], end = row_ptr[node + 1];
  #pragma unroll 4
  for (int i = beg; i < end; ++i) {
    int src = col_src[i];
    int eid = col_eid[i];
    const float4* eap = (eid < E) ? (const float4*)(ea + (size_t)eid * 16)
                                  : (const float4*)(loop_attr + (size_t)(eid - E) * 16);
    float2 xlv = ((const float2*)(xl + (size_t)src * 128))[lane];   // the gather
    float eh0 = 0.f, eh1 = 0.f;
    #pragma unroll
    for (int q = 0; q < 4; ++q) {
      float4 v = eap[q];
      eh0 += v.x * we0[q * 4 + 0] + v.y * we0[q * 4 + 1] + v.z * we0[q * 4 + 2] + v.w * we0[q * 4 + 3];
      eh1 += v.x * we1[q * 4 + 0] + v.y * we1[q * 4 + 1] + v.z * we1[q * 4 + 2] + v.w * we1[q * 4 + 3];
    }
    float m0 = xlv.x + xrv.x + eh0;
    float m1 = xlv.y + xrv.y + eh1;
    float l0 = m0 > 0.f ? m0 : 0.2f * m0;   // leaky_relu(0.2)
    float l1 = m1 > 0.f ? m1 : 0.2f * m1;
    float p = l0 * att0 + l1 * att1;
    p += __shfl_xor(p, 1);
    p += __shfl_xor(p, 2);
    p += __shfl_xor(p, 4);
    p += __shfl_xor(p, 8);                   // all 16 lanes now hold e_h
    float nm = fmaxf(mx, p);
    float sc = expf(mx - nm);                // first iter: expf(-inf)=0
    float w  = expf(p - nm);
    den  = den  * sc + w;
    acc0 = acc0 * sc + w * xlv.x;
    acc1 = acc1 * sc + w * xlv.y;
    mx = nm;
  }
  float inv = 1.f / (den + 1e-16f);
  float2 bv = ((const float2*)bvec)[lane];
  float o0 = acc0 * inv + bv.x;
  float o1 = acc1 * inv + bv.y;
  // exact GELU (approximate=False)
  o0 = 0.5f * o0 * (1.f + erff(o0 * 0.70710678118654752f));
  o1 = 0.5f * o1 * (1.f + erff(o1 * 0.70710678118654752f));
  ((float2*)(out + (size_t)node * 128))[lane] = make_float2(o0, o1);
}

// ---- classifier: logits = h @ Wc + bc --------------------------------------
__global__ void k_classifier(const float* __restrict__ h, const float* __restrict__ Wc,
                             const float* __restrict__ bc, float* __restrict__ out, int n) {
  int node = blockIdx.x * blockDim.x + threadIdx.x;
  if (node >= n) return;
  const float4* hp = (const float4*)(h + (size_t)node * 128);
  const float4* wp = (const float4*)Wc;
  float acc = 0.f;
  #pragma unroll
  for (int k = 0; k < 32; ++k) {
    float4 a = hp[k];
    float4 w = wp[k];
    acc += a.x * w.x + a.y * w.y + a.z * w.z + a.w * w.w;
  }
  out[node] = acc + bc[0];
}

// ---------------------------------------------------------------------------
extern "C" void kernel_launch(void* const* d_in, const int* in_sizes, int n_in,
                              void* d_out, int out_size, void* d_ws, size_t ws_size,
                              hipStream_t stream) {
  const float* x    = (const float*)d_in[0];
  const int*   ei   = (const int*)d_in[1];     // int32! (harness converts int64)
  const float* ea   = (const float*)d_in[2];
  const float* Wl0  = (const float*)d_in[3];
  const float* bl0  = (const float*)d_in[4];
  const float* Wr0  = (const float*)d_in[5];
  const float* br0  = (const float*)d_in[6];
  const float* We0  = (const float*)d_in[7];
  const float* att0 = (const float*)d_in[8];
  const float* b0   = (const float*)d_in[9];
  const float* Wl1  = (const float*)d_in[10];
  const float* bl1  = (const float*)d_in[11];
  const float* Wr1  = (const float*)d_in[12];
  const float* br1  = (const float*)d_in[13];
  const float* We1  = (const float*)d_in[14];
  const float* att1 = (const float*)d_in[15];
  const float* b1   = (const float*)d_in[16];
  const float* Wc   = (const float*)d_in[17];
  const float* bc   = (const float*)d_in[18];
  float* out = (float*)d_out;

  int n  = in_sizes[0] / 128;
  int E  = in_sizes[1] / 2;
  int Ep = E + n;

  char* ws = (char*)d_ws;
  size_t off = 0;
  auto alloc = [&](size_t bytes) { size_t o = off; off = align256(off + bytes); return o; };
  int*   cnt     = (int*)  (ws + alloc((size_t)n * 4));
  float* lsum    = (float*)(ws + alloc((size_t)n * 16 * 4));     // becomes loop_attr
  int*   row_ptr = (int*)  (ws + alloc((size_t)(n + 1) * 4));
  int*   cursor  = (int*)  (ws + alloc((size_t)n * 4));
  int*   col_src = (int*)  (ws + alloc((size_t)Ep * 4));
  int*   col_eid = (int*)  (ws + alloc((size_t)Ep * 4));
  float* xl      = (float*)(ws + alloc((size_t)n * 128 * 4));
  float* xr      = (float*)(ws + alloc((size_t)n * 128 * 4));
  float* hbuf    = (float*)(ws + alloc((size_t)n * 128 * 4));
  (void)ws_size; (void)n_in; (void)out_size;

  // --- graph preprocessing (identical work every call; ws is re-poisoned) ---
  hipMemsetAsync(cnt, 0, (size_t)n * 4, stream);
  hipMemsetAsync(lsum, 0, (size_t)n * 64, stream);
  k_loop_accum<<<(E * 16 + 255) / 256, 256, 0, stream>>>(ei, ea, lsum, cnt, E, n);
  k_loop_final<<<(n * 16 + 255) / 256, 256, 0, stream>>>(lsum, cnt, n);
  k_scan<<<1, 512, 0, stream>>>(cnt, row_ptr, n);
  hipMemcpyAsync(cursor, row_ptr, (size_t)n * 4, hipMemcpyDeviceToDevice, stream);
  k_scatter<<<(Ep + 255) / 256, 256, 0, stream>>>(ei, cursor, col_src, col_eid, E, n);

  // --- layer 0 ---
  k_transform<<<(n + 15) / 16, 256, 0, stream>>>(x, Wl0, bl0, Wr0, br0, xl, xr, n);
  k_aggregate<<<(n + 3) / 4, 256, 0, stream>>>(xl, xr, row_ptr, col_src, col_eid,
                                               ea, lsum, We0, att0, b0, hbuf, n, E);
  // --- layer 1 (hbuf is input; aggregation only reads xl/xr, so hbuf reuse is safe) ---
  k_transform<<<(n + 15) / 16, 256, 0, stream>>>(hbuf, Wl1, bl1, Wr1, br1, xl, xr, n);
  k_aggregate<<<(n + 3) / 4, 256, 0, stream>>>(xl, xr, row_ptr, col_src, col_eid,
                                               ea, lsum, We1, att1, b1, hbuf, n, E);
  // --- classifier ---
  k_classifier<<<(n + 255) / 256, 256, 0, stream>>>(hbuf, Wc, bc, out, n);
}

// Round 7
// 821.011 us; speedup vs baseline: 1.1034x; 1.1034x over previous
//
#include <hip/hip_runtime.h>
#include <math.h>

// ---------------------------------------------------------------------------
// GATv2 2-layer GNN (N=50000, E=800000, IN=W=128, HEADS=4, HID=32, EDIM=16)
// R5 baseline: 906 us total; k_aggregate 233 us x2 (VALU 66%, occ 56%, HBM 16%).
// R6: (1) aggregate: scalarized uniform loads (int2 CSR pairs, readfirstlane),
//         2-stream online softmax + unroll -> ILP, __expf, fmax-leaky.
//     (2) loop_attr via CSR mean (no float atomics) replacing 12.8M-atomic pass.
//     (3) scan block 1024.
// NOTE: harness passes integer inputs as int32 ("integer -> const int*").
// ---------------------------------------------------------------------------

static inline size_t align256(size_t x) { return (x + 255) & ~size_t(255); }

__device__ __forceinline__ int clampi(int v, int lo, int hi) {
  return v < lo ? lo : (v > hi ? hi : v);
}

// ---- in-degree histogram (int atomics only) --------------------------------
__global__ void k_hist(const int* __restrict__ ei, int* __restrict__ cnt, int E, int n) {
  int i = blockIdx.x * blockDim.x + threadIdx.x;
  if (i >= E) return;
  int dst = clampi(ei[E + i], 0, n - 1);
  atomicAdd(&cnt[dst], 1);
}

// ---- exclusive scan of (cnt[i]+1) over n nodes, single block of 1024 -------
__global__ void k_scan(const int* __restrict__ cnt, int* __restrict__ row_ptr, int n) {
  const int T = 1024;
  __shared__ int wsum[16], wbase[16];
  int tid = threadIdx.x;
  int chunk = (n + T - 1) / T;
  int lo = tid * chunk; if (lo > n) lo = n;
  int hi = lo + chunk;  if (hi > n) hi = n;
  int s = 0;
  for (int i = lo; i < hi; ++i) s += cnt[i] + 1;
  int lane = tid & 63, w = tid >> 6;
  int incl = s;
  #pragma unroll
  for (int d = 1; d < 64; d <<= 1) {
    int v = __shfl_up(incl, d, 64);
    if (lane >= d) incl += v;
  }
  if (lane == 63) wsum[w] = incl;
  __syncthreads();
  if (tid == 0) {
    int a = 0;
    for (int i = 0; i < 16; ++i) { wbase[i] = a; a += wsum[i]; }
  }
  __syncthreads();
  int run = wbase[w] + (incl - s);   // exclusive prefix at this thread's chunk
  if (tid == 0) row_ptr[0] = 0;
  for (int i = lo; i < hi; ++i) { run += cnt[i] + 1; row_ptr[i + 1] = run; }
}

// ---- scatter edges (and self-loops) into CSR as int2{src,eid} --------------
__global__ void k_scatter(const int* __restrict__ ei, int* __restrict__ cursor,
                          int2* __restrict__ col, int E, int n) {
  int i = blockIdx.x * blockDim.x + threadIdx.x;
  if (i < E) {
    int src = clampi(ei[i], 0, n - 1);
    int dst = clampi(ei[E + i], 0, n - 1);
    int pos = atomicAdd(&cursor[dst], 1);
    col[pos] = make_int2(src, i);
  } else if (i < E + n) {
    int node = i - E;
    int pos = atomicAdd(&cursor[node], 1);
    col[pos] = make_int2(node, E + node);   // eid >= E marks the self-loop
  }
}

// ---- self-loop attr = mean of incoming ORIGINAL edge_attr, via CSR ---------
// thread t -> (node, dim); skips the self-loop entry (eid >= E). No atomics.
__global__ void k_loop_mean(const int* __restrict__ row_ptr, const int2* __restrict__ col,
                            const float* __restrict__ ea, float* __restrict__ lsum,
                            int n, int E) {
  int t = blockIdx.x * blockDim.x + threadIdx.x;
  if (t >= n * 16) return;
  int node = t >> 4, d = t & 15;
  int beg = row_ptr[node], end = row_ptr[node + 1];
  float s = 0.f;
  int c = 0;
  for (int i = beg; i < end; ++i) {
    int2 se = col[i];
    if (se.y < E) { s += ea[(size_t)se.y * 16 + d]; ++c; }
  }
  lsum[t] = s / (float)(c > 0 ? c : 1);
}

// ---- node transform: xl = in@Wl+bl, xr = in@Wr+br (fused, 256 cols) --------
__launch_bounds__(256)
__global__ void k_transform(const float* __restrict__ in, const float* __restrict__ Wl,
                            const float* __restrict__ bl, const float* __restrict__ Wr,
                            const float* __restrict__ br, float* __restrict__ xl,
                            float* __restrict__ xr, int n) {
  __shared__ float As[16][128];
  int tid = threadIdx.x;
  int row0 = blockIdx.x * 16;
  int rows = n - row0; if (rows > 16) rows = 16;
  const float4* in4 = (const float4*)(in + (size_t)row0 * 128);
  float4* As4 = (float4*)As;
  for (int i = tid; i < rows * 32; i += 256) As4[i] = in4[i];
  __syncthreads();
  int c = tid;
  const float* B = (c < 128) ? Wl : Wr;
  int cc = c & 127;
  float bias = (c < 128) ? bl[cc] : br[cc];
  float acc[16];
  #pragma unroll
  for (int i = 0; i < 16; ++i) acc[i] = bias;
  for (int k = 0; k < 128; k += 4) {
    float b0 = B[(k + 0) * 128 + cc], b1 = B[(k + 1) * 128 + cc];
    float b2 = B[(k + 2) * 128 + cc], b3 = B[(k + 3) * 128 + cc];
    #pragma unroll
    for (int r = 0; r < 16; ++r) {
      float4 a = *(const float4*)&As[r][k];   // LDS broadcast (uniform addr)
      acc[r] += a.x * b0 + a.y * b1 + a.z * b2 + a.w * b3;
    }
  }
  float* op = (c < 128) ? xl : xr;
  for (int r = 0; r < rows; ++r) op[(size_t)(row0 + r) * 128 + cc] = acc[r];
}

// ---- GATv2 aggregation: one wave per node, 2-stream online softmax ---------
// lane -> channels (2*lane, 2*lane+1), head = lane>>4.
// Wave-uniform CSR entries readfirstlane'd -> scalar loads for col/ea.
// One EDGE_STEP per macro call; two independent (mx,den,acc) streams for ILP.
#define EDGE_STEP(SRC, EID, MX, DEN, A0, A1)                                     \
  do {                                                                           \
    const float* ep = ((EID) < E) ? (ea + (size_t)(EID) * 16)                    \
                                  : (loop_attr + (size_t)((EID) - E) * 16);      \
    float2 xlv = *(const float2*)(xl + (size_t)(SRC) * 128 + lane * 2);          \
    float4 v0 = ((const float4*)ep)[0];                                          \
    float4 v1 = ((const float4*)ep)[1];                                          \
    float4 v2 = ((const float4*)ep)[2];                                          \
    float4 v3 = ((const float4*)ep)[3];                                          \
    float eh0 = v0.x * we0[0] + v0.y * we0[1] + v0.z * we0[2] + v0.w * we0[3];   \
    float eh1 = v0.x * we1[0] + v0.y * we1[1] + v0.z * we1[2] + v0.w * we1[3];   \
    eh0 += v1.x * we0[4] + v1.y * we0[5] + v1.z * we0[6] + v1.w * we0[7];        \
    eh1 += v1.x * we1[4] + v1.y * we1[5] + v1.z * we1[6] + v1.w * we1[7];        \
    eh0 += v2.x * we0[8] + v2.y * we0[9] + v2.z * we0[10] + v2.w * we0[11];      \
    eh1 += v2.x * we1[8] + v2.y * we1[9] + v2.z * we1[10] + v2.w * we1[11];      \
    eh0 += v3.x * we0[12] + v3.y * we0[13] + v3.z * we0[14] + v3.w * we0[15];    \
    eh1 += v3.x * we1[12] + v3.y * we1[13] + v3.z * we1[14] + v3.w * we1[15];    \
    float m0 = xlv.x + xrv.x + eh0;                                              \
    float m1 = xlv.y + xrv.y + eh1;                                              \
    float l0 = fmaxf(m0, 0.2f * m0);  /* leaky_relu(0.2) */                      \
    float l1 = fmaxf(m1, 0.2f * m1);                                             \
    float p = l0 * att0 + l1 * att1;                                             \
    p += __shfl_xor(p, 1);                                                       \
    p += __shfl_xor(p, 2);                                                       \
    p += __shfl_xor(p, 4);                                                       \
    p += __shfl_xor(p, 8);                                                       \
    float nm = fmaxf(MX, p);                                                     \
    float sc = __expf(MX - nm);                                                  \
    float w  = __expf(p - nm);                                                   \
    DEN = DEN * sc + w;                                                          \
    A0  = A0 * sc + w * xlv.x;                                                   \
    A1  = A1 * sc + w * xlv.y;                                                   \
    MX  = nm;                                                                    \
  } while (0)

__launch_bounds__(256)
__global__ void k_aggregate(const float* __restrict__ xl, const float* __restrict__ xr,
                            const int* __restrict__ row_ptr, const int2* __restrict__ col,
                            const float* __restrict__ ea, const float* __restrict__ loop_attr,
                            const float* __restrict__ We, const float* __restrict__ att,
                            const float* __restrict__ bvec, float* __restrict__ out,
                            int n, int E) {
  int wv = threadIdx.x >> 6, lane = threadIdx.x & 63;
  int node = blockIdx.x * 4 + wv;
  if (node >= n) return;
  int c0 = lane * 2, c1 = lane * 2 + 1;
  float we0[16], we1[16];
  #pragma unroll
  for (int d = 0; d < 16; ++d) {
    we0[d] = We[d * 128 + c0];
    we1[d] = We[d * 128 + c1];
  }
  float att0 = att[c0], att1 = att[c1];
  float2 xrv = *(const float2*)(xr + (size_t)node * 128 + lane * 2);
  // wave-uniform row bounds -> scalar loop
  int beg = __builtin_amdgcn_readfirstlane(row_ptr[node]);
  int end = __builtin_amdgcn_readfirstlane(row_ptr[node + 1]);
  float mA = -INFINITY, dA = 0.f, a0A = 0.f, a1A = 0.f;
  float mB = -INFINITY, dB = 0.f, a0B = 0.f, a1B = 0.f;
  int i = beg;
  #pragma unroll 2
  for (; i + 1 < end; i += 2) {
    int2 sa = col[i];
    int2 sb = col[i + 1];
    int srcA = __builtin_amdgcn_readfirstlane(sa.x);
    int eidA = __builtin_amdgcn_readfirstlane(sa.y);
    int srcB = __builtin_amdgcn_readfirstlane(sb.x);
    int eidB = __builtin_amdgcn_readfirstlane(sb.y);
    EDGE_STEP(srcA, eidA, mA, dA, a0A, a1A);
    EDGE_STEP(srcB, eidB, mB, dB, a0B, a1B);
  }
  if (i < end) {
    int2 sa = col[i];
    int srcA = __builtin_amdgcn_readfirstlane(sa.x);
    int eidA = __builtin_amdgcn_readfirstlane(sa.y);
    EDGE_STEP(srcA, eidA, mA, dA, a0A, a1A);
  }
  // merge the two streams (deg>=1 guarantees mA finite; mB may be -inf -> eB=0)
  float nm = fmaxf(mA, mB);
  float eA = __expf(mA - nm), eB = __expf(mB - nm);
  float den  = dA * eA + dB * eB;
  float acc0 = a0A * eA + a0B * eB;
  float acc1 = a1A * eA + a1B * eB;
  float inv = 1.f / (den + 1e-16f);
  float2 bv = ((const float2*)bvec)[lane];
  float o0 = acc0 * inv + bv.x;
  float o1 = acc1 * inv + bv.y;
  // exact GELU (approximate=False)
  o0 = 0.5f * o0 * (1.f + erff(o0 * 0.70710678118654752f));
  o1 = 0.5f * o1 * (1.f + erff(o1 * 0.70710678118654752f));
  *(float2*)(out + (size_t)node * 128 + lane * 2) = make_float2(o0, o1);
}

// ---- classifier: logits = h @ Wc + bc --------------------------------------
__global__ void k_classifier(const float* __restrict__ h, const float* __restrict__ Wc,
                             const float* __restrict__ bc, float* __restrict__ out, int n) {
  int node = blockIdx.x * blockDim.x + threadIdx.x;
  if (node >= n) return;
  const float4* hp = (const float4*)(h + (size_t)node * 128);
  const float4* wp = (const float4*)Wc;
  float acc = 0.f;
  #pragma unroll
  for (int k = 0; k < 32; ++k) {
    float4 a = hp[k];
    float4 w = wp[k];
    acc += a.x * w.x + a.y * w.y + a.z * w.z + a.w * w.w;
  }
  out[node] = acc + bc[0];
}

// ---------------------------------------------------------------------------
extern "C" void kernel_launch(void* const* d_in, const int* in_sizes, int n_in,
                              void* d_out, int out_size, void* d_ws, size_t ws_size,
                              hipStream_t stream) {
  const float* x    = (const float*)d_in[0];
  const int*   ei   = (const int*)d_in[1];     // int32 (harness converts int64)
  const float* ea   = (const float*)d_in[2];
  const float* Wl0  = (const float*)d_in[3];
  const float* bl0  = (const float*)d_in[4];
  const float* Wr0  = (const float*)d_in[5];
  const float* br0  = (const float*)d_in[6];
  const float* We0  = (const float*)d_in[7];
  const float* att0 = (const float*)d_in[8];
  const float* b0   = (const float*)d_in[9];
  const float* Wl1  = (const float*)d_in[10];
  const float* bl1  = (const float*)d_in[11];
  const float* Wr1  = (const float*)d_in[12];
  const float* br1  = (const float*)d_in[13];
  const float* We1  = (const float*)d_in[14];
  const float* att1 = (const float*)d_in[15];
  const float* b1   = (const float*)d_in[16];
  const float* Wc   = (const float*)d_in[17];
  const float* bc   = (const float*)d_in[18];
  float* out = (float*)d_out;

  int n  = in_sizes[0] / 128;
  int E  = in_sizes[1] / 2;
  int Ep = E + n;

  char* ws = (char*)d_ws;
  size_t off = 0;
  auto alloc = [&](size_t bytes) { size_t o = off; off = align256(off + bytes); return o; };
  int*   cnt     = (int*)  (ws + alloc((size_t)n * 4));
  float* lsum    = (float*)(ws + alloc((size_t)n * 16 * 4));     // loop_attr
  int*   row_ptr = (int*)  (ws + alloc((size_t)(n + 1) * 4));
  int*   cursor  = (int*)  (ws + alloc((size_t)n * 4));
  int2*  col     = (int2*) (ws + alloc((size_t)Ep * 8));
  float* xl      = (float*)(ws + alloc((size_t)n * 128 * 4));
  float* xr      = (float*)(ws + alloc((size_t)n * 128 * 4));
  float* hbuf    = (float*)(ws + alloc((size_t)n * 128 * 4));
  (void)ws_size; (void)n_in; (void)out_size;

  // --- graph preprocessing (identical work every call) ---
  hipMemsetAsync(cnt, 0, (size_t)n * 4, stream);
  k_hist<<<(E + 255) / 256, 256, 0, stream>>>(ei, cnt, E, n);
  k_scan<<<1, 1024, 0, stream>>>(cnt, row_ptr, n);
  hipMemcpyAsync(cursor, row_ptr, (size_t)n * 4, hipMemcpyDeviceToDevice, stream);
  k_scatter<<<(Ep + 255) / 256, 256, 0, stream>>>(ei, cursor, col, E, n);
  k_loop_mean<<<(n * 16 + 255) / 256, 256, 0, stream>>>(row_ptr, col, ea, lsum, n, E);

  // --- layer 0 ---
  k_transform<<<(n + 15) / 16, 256, 0, stream>>>(x, Wl0, bl0, Wr0, br0, xl, xr, n);
  k_aggregate<<<(n + 3) / 4, 256, 0, stream>>>(xl, xr, row_ptr, col, ea, lsum,
                                               We0, att0, b0, hbuf, n, E);
  // --- layer 1 ---
  k_transform<<<(n + 15) / 16, 256, 0, stream>>>(hbuf, Wl1, bl1, Wr1, br1, xl, xr, n);
  k_aggregate<<<(n + 3) / 4, 256, 0, stream>>>(xl, xr, row_ptr, col, ea, lsum,
                                               We1, att1, b1, hbuf, n, E);
  // --- classifier ---
  k_classifier<<<(n + 255) / 256, 256, 0, stream>>>(hbuf, Wc, bc, out, n);
}